// Round 9
// baseline (306.141 us; speedup 1.0000x reference)
//
#include <hip/hip_runtime.h>

typedef short v8s __attribute__((ext_vector_type(8)));
typedef float v4f __attribute__((ext_vector_type(4)));
typedef float v2f __attribute__((ext_vector_type(2)));

#define NSP 32768
#define XSTR 2056            // bytes per w-location in Xbuf (8B aligned, bank-staggered)
#define WS_ZP_B 65536ull     // zp region byte offset in ws

__device__ __forceinline__ unsigned short f2bf(float f) {
  union { float f; unsigned u; } v; v.f = f;
  unsigned r = v.u + 0x7fffu + ((v.u >> 16) & 1u);
  return (unsigned short)(r >> 16);
}
__device__ __forceinline__ unsigned pk(float a, float b) {
  return (unsigned)f2bf(a) | ((unsigned)f2bf(b) << 16);
}

union UF8 { v8s v; unsigned u[4]; uint4 q; };

// k-map convention used CONSISTENTLY for every A and B fragment (errors cancel):
// frag element j of lane (i16 + 16*g) <-> k = 16*(j>>2) + 4*g + (j&3)

__global__ __launch_bounds__(512) void prep_kernel(
    const float* __restrict__ Wk, const float* __restrict__ bk,
    const float* __restrict__ Wq, const float* __restrict__ bq,
    const float* __restrict__ Wv, unsigned* __restrict__ ws) {
  __shared__ float sWk[4096], sWq[4096], sWv[4096], sbk[64], sbq[64];
  for (int i = threadIdx.x; i < 4096; i += 512) { sWk[i] = Wk[i]; sWq[i] = Wq[i]; sWv[i] = Wv[i]; }
  if (threadIdx.x < 64) { sbk[threadIdx.x] = bk[threadIdx.x]; sbq[threadIdx.x] = bq[threadIdx.x]; }
  __syncthreads();
  for (int task = threadIdx.x; task < 18 * 64; task += 512) {
    int f = task >> 6, lane = task & 63;
    int i16 = lane & 15, g = lane >> 4;
    unsigned short e[8];
    #pragma unroll
    for (int j = 0; j < 8; ++j) {
      int k = (((j >> 2) << 4) + 4 * g + (j & 3));
      float acc = 0.f;
      if (f < 8) {
        int row = ((f >> 1) << 4) + i16;
        int cc  = ((f & 1) << 5) + k;
        for (int a = 0; a < 64; ++a) acc += sWk[a * 64 + row] * sWq[a * 64 + cc];
      } else if (f < 10) {
        int c = ((f - 8) << 5) + k;
        if (i16 == 0)      { for (int a = 0; a < 64; ++a) acc += sWk[a * 64 + c] * sbq[a]; }
        else if (i16 == 1) { for (int a = 0; a < 64; ++a) acc += sbk[a] * sWq[a * 64 + c]; }
      } else {
        int c  = (((f - 10) >> 1) << 4) + i16;
        int cp = (((f - 10) & 1) << 5) + k;
        acc = sWv[c * 64 + cp];
      }
      e[j] = f2bf(acc);
    }
    unsigned* dst = ws + (size_t)(f * 64 + lane) * 4;
    dst[0] = e[0] | ((unsigned)e[1] << 16);
    dst[1] = e[2] | ((unsigned)e[3] << 16);
    dst[2] = e[4] | ((unsigned)e[5] << 16);
    dst[3] = e[6] | ((unsigned)e[7] << 16);
  }
  if (threadIdx.x == 0) {
    float beta = 0.f;
    for (int a = 0; a < 64; ++a) beta += sbk[a] * sbq[a];
    ((float*)ws)[18 * 256] = beta;
  }
}

#define S2L 0.18033688011112042f  /* (1/8) * log2(e) */

#define DECODE512() \
  int bid = (int)blockIdx.x; \
  int b = bid & 1, dcc = (bid >> 1) & 7, h = bid >> 4; \
  const int d0 = dcc << 2; \
  const size_t base0 = (size_t)b * 33554432 + h * 32;

// half-slice staging: 32 regs peak; issueH/writeH pairs
#define STAGE_DEFS(BUF) \
  const int w2 = tid & 15; \
  const int rp0 = tid >> 4; \
  v2f sA[8], sB[8]; \
  auto issueH = [&](int d, int half) { \
    const float* xp = x + base0 + (size_t)d * 1024; \
    _Pragma("unroll") \
    for (int i = 0; i < 8; ++i) { \
      int rp = half * 256 + (i << 5) + rp0; \
      const float* r0 = xp + (size_t)(2 * rp) * NSP + 2 * w2; \
      sA[i] = *(const v2f*)r0; \
      sB[i] = *(const v2f*)(r0 + NSP); \
    } \
  }; \
  auto writeH = [&](int half) { \
    _Pragma("unroll") \
    for (int i = 0; i < 8; ++i) { \
      int rp = half * 256 + (i << 5) + rp0; \
      int t = rp >> 5, c = (rp & 31) << 1; \
      int off = (t << 7) + (((c << 1)) ^ ((t & 7) << 4)); \
      *(unsigned*)(&BUF[(2 * w2) * XSTR + off])     = pk(sA[i].x, sB[i].x); \
      *(unsigned*)(&BUF[(2 * w2 + 1) * XSTR + off]) = pk(sA[i].y, sB[i].y); \
    } \
  };

#define LOADX_DEF(BUF) \
  auto loadX = [&](int loc, v8s fX[2]) { \
    const unsigned char* bp = &BUF[loc * XSTR + (i16 << 7)]; \
    const int sw = (i16 & 7) << 4; \
    _Pragma("unroll") \
    for (int kc = 0; kc < 2; ++kc) { \
      union { v8s v; unsigned long long dd[2]; } u; \
      int o = (kc << 6) + (g << 3); \
      u.dd[0] = *(const unsigned long long*)(bp + (o ^ sw)); \
      u.dd[1] = *(const unsigned long long*)(bp + ((o + 32) ^ sw)); \
      fX[kc] = u.v; \
    } \
  };

// fM (f=0..7) and fUR (f=8,9) fragments read from LDS per use
#define LDF_DEF() \
  auto ldf = [&](int f) -> v8s { \
    union { v8s v; uint4 q; } u; \
    u.q = *(const uint4*)&Wm[(f << 8) + (lane << 2)]; \
    return u.v; \
  };

#define ATTOF_DEF() \
  auto attOf = [&](const v8s fX[2]) -> v4f { \
    v4f accW[4]; \
    _Pragma("unroll") \
    for (int tr = 0; tr < 4; ++tr) { \
      v8s m0 = ldf(2 * tr), m1 = ldf(2 * tr + 1); \
      v4f a = {0.f, 0.f, 0.f, 0.f}; \
      a = __builtin_amdgcn_mfma_f32_16x16x32_bf16(m0, fX[0], a, 0, 0, 0); \
      a = __builtin_amdgcn_mfma_f32_16x16x32_bf16(m1, fX[1], a, 0, 0, 0); \
      accW[tr] = a; \
    } \
    v8s u0 = ldf(8), u1 = ldf(9); \
    v4f au = {0.f, 0.f, 0.f, 0.f}; \
    au = __builtin_amdgcn_mfma_f32_16x16x32_bf16(u0, fX[0], au, 0, 0, 0); \
    au = __builtin_amdgcn_mfma_f32_16x16x32_bf16(u1, fX[1], au, 0, 0, 0); \
    float a1v = au[0] + beta; \
    float a2v = au[1]; \
    float a2s = __shfl(a2v, i16); \
    v4f att; \
    _Pragma("unroll") \
    for (int j = 0; j < 4; ++j) att[j] = __shfl(a1v, 4 * g + j) + a2s; \
    _Pragma("unroll") \
    for (int kc = 0; kc < 2; ++kc) { \
      UF8 w; \
      w.u[0] = pk(accW[2 * kc][0], accW[2 * kc][1]); \
      w.u[1] = pk(accW[2 * kc][2], accW[2 * kc][3]); \
      w.u[2] = pk(accW[2 * kc + 1][0], accW[2 * kc + 1][1]); \
      w.u[3] = pk(accW[2 * kc + 1][2], accW[2 * kc + 1][3]); \
      att = __builtin_amdgcn_mfma_f32_16x16x32_bf16(fX[kc], w.v, att, 0, 0, 0); \
    } \
    return att; \
  };

// feat MFMA for one c-quarter (tn literal!) -> Fb buffer with bank XOR
#define FEATQ(tn, FB) do { \
  _Pragma("unroll") \
  for (int l = 0; l < 4; ++l) { \
    int wq = 4 * wv + l; \
    UF8 fP; fP.u[0] = Pp[l][0]; fP.u[1] = Pp[l][1]; fP.u[2] = 0; fP.u[3] = 0; \
    UF8 fV; fV.u[0] = vp[l][2 * (tn)]; fV.u[1] = vp[l][2 * (tn) + 1]; fV.u[2] = 0; fV.u[3] = 0; \
    v4f ft = {0.f, 0.f, 0.f, 0.f}; \
    ft = __builtin_amdgcn_mfma_f32_16x16x32_bf16(fP.v, fV.v, ft, 0, 0, 0); \
    _Pragma("unroll") \
    for (int j = 0; j < 4; ++j) { \
      int r = (4 * g + j) * 16 + i16; \
      (FB)[r * 33 + (wq ^ g)] = ft[j]; \
    } \
  } \
} while (0)

// ---------------- pass 1: partial Z over a 4-slice d-chunk ----------------
__global__ __launch_bounds__(512) void pass1_z(
    const float* __restrict__ x, const unsigned* __restrict__ ws,
    float* __restrict__ zp) {
  __shared__ __align__(16) unsigned char Xbuf[32 * XSTR];   // 65792 B
  __shared__ unsigned Wm[2560];                             // 10240 B  (total 76032)

  const int tid = (int)threadIdx.x;
  const int lane = tid & 63, wv = tid >> 6;
  const int i16 = lane & 15, g = lane >> 4;
  DECODE512();

  for (int o = tid; o < 2560; o += 512) Wm[o] = ws[o];
  const float beta = ((const float*)ws)[4608];

  STAGE_DEFS(Xbuf);
  LOADX_DEF(Xbuf);
  LDF_DEF();
  ATTOF_DEF();

  float Z[4][4] = {};
  issueH(d0, 0);
  for (int ii = 0; ii < 4; ++ii) {
    const int d = d0 + ii;
    __syncthreads();                 // prev readers done (also covers Wm copy)
    writeH(0);
    issueH(d, 1);
    writeH(1);
    __syncthreads();                 // stage complete
    if (ii < 3) issueH(d + 1, 0);    // prefetch flies during compute
    #pragma unroll
    for (int l = 0; l < 4; ++l) {
      v8s fX[2]; loadX(4 * wv + l, fX);
      v4f att = attOf(fX);
      #pragma unroll
      for (int j = 0; j < 4; ++j) Z[l][j] += exp2f(att[j] * S2L);
    }
  }
  const int locg = b * 1024 + h * 32 + 4 * wv;
  #pragma unroll
  for (int l = 0; l < 4; ++l)
    #pragma unroll
    for (int j = 0; j < 4; ++j)
      zp[(((size_t)dcc * 2048 + locg + l) << 8) + (4 * g + j) * 16 + i16] = Z[l][j];
}

// ---------------- pass 2: P, v, feat, out; single Fb aliased on Xbuf ----------------
__global__ __launch_bounds__(512) void pass2_out(
    const float* __restrict__ x, const float* __restrict__ bv,
    const unsigned* __restrict__ ws, const float* __restrict__ zp,
    float* __restrict__ out) {
  __shared__ __align__(16) unsigned char UNI[65792];        // Xbuf / Fb (33792) overlay
  __shared__ unsigned Wm[2560];                             // total 76032 B

  const int tid = (int)threadIdx.x;
  const int lane = tid & 63, wv = tid >> 6;
  const int i16 = lane & 15, g = lane >> 4;
  DECODE512();

  for (int o = tid; o < 2560; o += 512) Wm[o] = ws[o];
  const float beta = ((const float*)ws)[4608];
  float bvv[4];
  #pragma unroll
  for (int tn = 0; tn < 4; ++tn) bvv[tn] = bv[i16 + 16 * tn];

  // 1/Z from the 8 chunk partials
  float iZ[4][4];
  #pragma unroll
  for (int l = 0; l < 4; ++l) {
    const int locg = b * 1024 + h * 32 + 4 * wv + l;
    #pragma unroll
    for (int j = 0; j < 4; ++j) {
      float s = 0.f;
      #pragma unroll
      for (int c2 = 0; c2 < 8; ++c2)
        s += zp[(((size_t)c2 * 2048 + locg) << 8) + (4 * g + j) * 16 + i16];
      iZ[l][j] = 1.f / s;
    }
  }

  STAGE_DEFS(UNI);
  LOADX_DEF(UNI);
  LDF_DEF();
  ATTOF_DEF();

  float* Fb = (float*)UNI;
  const uint4* W4 = (const uint4*)ws;

  auto storeQ = [&](int tn, int d) {
    float* op = out + base0 + (size_t)d * 1024 + (size_t)(16 * tn) * NSP;
    const int w4 = tid & 7, rr = tid >> 3;
    #pragma unroll
    for (int it = 0; it < 4; ++it) {
      int r = (it << 6) + rr;
      const float* fp = &Fb[r * 33 + (w4 << 2)];
      float4 val;
      val.x = fp[0 ^ it]; val.y = fp[1 ^ it]; val.z = fp[2 ^ it]; val.w = fp[3 ^ it];
      *(float4*)(op + (size_t)((r >> 4) * 64 + (r & 15)) * NSP + (w4 << 2)) = val;
    }
  };

  issueH(d0, 0);
  for (int ii = 0; ii < 4; ++ii) {
    const int d = d0 + ii;
    __syncthreads();                 // prev storeQ(3) LDS reads done -> UNI writable
    writeH(0);
    issueH(d, 1);
    writeH(1);
    __syncthreads();                 // stage complete

    // ---- P and v for all 4 locs into registers (no stage regs live here) ----
    unsigned Pp[4][2], vp[4][8];
    #pragma unroll
    for (int l = 0; l < 4; ++l) {
      v8s fX[2]; loadX(4 * wv + l, fX);
      v4f att = attOf(fX);
      float p0 = exp2f(att[0] * S2L) * iZ[l][0];
      float p1 = exp2f(att[1] * S2L) * iZ[l][1];
      float p2 = exp2f(att[2] * S2L) * iZ[l][2];
      float p3 = exp2f(att[3] * S2L) * iZ[l][3];
      Pp[l][0] = pk(p0, p1); Pp[l][1] = pk(p2, p3);
      #pragma unroll
      for (int tn = 0; tn < 4; ++tn) {
        UF8 wa, wb;
        wa.q = W4[(10 + 2 * tn) * 64 + lane];
        wb.q = W4[(11 + 2 * tn) * 64 + lane];
        v4f a = {bvv[tn], bvv[tn], bvv[tn], bvv[tn]};
        a = __builtin_amdgcn_mfma_f32_16x16x32_bf16(fX[0], wa.v, a, 0, 0, 0);
        a = __builtin_amdgcn_mfma_f32_16x16x32_bf16(fX[1], wb.v, a, 0, 0, 0);
        vp[l][2 * tn] = pk(a[0], a[1]); vp[l][2 * tn + 1] = pk(a[2], a[3]);
      }
    }
    __syncthreads();                 // all Xbuf reads done -> Fb overlay safe

    FEATQ(0, Fb);
    __syncthreads();
    storeQ(0, d);
    __syncthreads();
    FEATQ(1, Fb);
    __syncthreads();
    storeQ(1, d);
    __syncthreads();
    FEATQ(2, Fb);
    __syncthreads();
    storeQ(2, d);
    __syncthreads();
    FEATQ(3, Fb);
    if (ii < 3) issueH(d + 1, 0);    // prefetch overlaps final sync + store
    __syncthreads();
    storeQ(3, d);
  }
}

extern "C" void kernel_launch(void* const* d_in, const int* in_sizes, int n_in,
                              void* d_out, int out_size, void* d_ws, size_t ws_size,
                              hipStream_t stream) {
  const float* x  = (const float*)d_in[0];
  const float* Wk = (const float*)d_in[1];
  const float* bk = (const float*)d_in[2];
  const float* Wq = (const float*)d_in[3];
  const float* bq = (const float*)d_in[4];
  const float* Wv = (const float*)d_in[5];
  const float* bv = (const float*)d_in[6];
  float* out = (float*)d_out;
  unsigned* ws = (unsigned*)d_ws;
  float* zp = (float*)((char*)d_ws + WS_ZP_B);

  prep_kernel<<<1, 512, 0, stream>>>(Wk, bk, Wq, bq, Wv, ws);
  pass1_z<<<512, 512, 0, stream>>>(x, ws, zp);
  pass2_out<<<512, 512, 0, stream>>>(x, bv, ws, zp, out);
}

// Round 10
// 304.946 us; speedup vs baseline: 1.0039x; 1.0039x over previous
//
#include <hip/hip_runtime.h>

typedef short v8s __attribute__((ext_vector_type(8)));
typedef float v4f __attribute__((ext_vector_type(4)));
typedef float v2f __attribute__((ext_vector_type(2)));

#define NSP 32768
#define XSTR 2056            // bytes per w-location in Xbuf (8B aligned, bank-staggered)
#define WS_ZP_B 65536ull     // zp region byte offset in ws

__device__ __forceinline__ unsigned short f2bf(float f) {
  union { float f; unsigned u; } v; v.f = f;
  unsigned r = v.u + 0x7fffu + ((v.u >> 16) & 1u);
  return (unsigned short)(r >> 16);
}
__device__ __forceinline__ unsigned pk(float a, float b) {
  return (unsigned)f2bf(a) | ((unsigned)f2bf(b) << 16);
}

union UF8 { v8s v; unsigned u[4]; uint4 q; };

// k-map convention used CONSISTENTLY for every A and B fragment (errors cancel):
// frag element j of lane (i16 + 16*g) <-> k = 16*(j>>2) + 4*g + (j&3)

__global__ __launch_bounds__(512) void prep_kernel(
    const float* __restrict__ Wk, const float* __restrict__ bk,
    const float* __restrict__ Wq, const float* __restrict__ bq,
    const float* __restrict__ Wv, unsigned* __restrict__ ws) {
  __shared__ float sWk[4096], sWq[4096], sWv[4096], sbk[64], sbq[64];
  for (int i = threadIdx.x; i < 4096; i += 512) { sWk[i] = Wk[i]; sWq[i] = Wq[i]; sWv[i] = Wv[i]; }
  if (threadIdx.x < 64) { sbk[threadIdx.x] = bk[threadIdx.x]; sbq[threadIdx.x] = bq[threadIdx.x]; }
  __syncthreads();
  for (int task = threadIdx.x; task < 18 * 64; task += 512) {
    int f = task >> 6, lane = task & 63;
    int i16 = lane & 15, g = lane >> 4;
    unsigned short e[8];
    #pragma unroll
    for (int j = 0; j < 8; ++j) {
      int k = (((j >> 2) << 4) + 4 * g + (j & 3));
      float acc = 0.f;
      if (f < 8) {
        int row = ((f >> 1) << 4) + i16;
        int cc  = ((f & 1) << 5) + k;
        for (int a = 0; a < 64; ++a) acc += sWk[a * 64 + row] * sWq[a * 64 + cc];
      } else if (f < 10) {
        int c = ((f - 8) << 5) + k;
        if (i16 == 0)      { for (int a = 0; a < 64; ++a) acc += sWk[a * 64 + c] * sbq[a]; }
        else if (i16 == 1) { for (int a = 0; a < 64; ++a) acc += sbk[a] * sWq[a * 64 + c]; }
      } else {
        int c  = (((f - 10) >> 1) << 4) + i16;
        int cp = (((f - 10) & 1) << 5) + k;
        acc = sWv[c * 64 + cp];
      }
      e[j] = f2bf(acc);
    }
    unsigned* dst = ws + (size_t)(f * 64 + lane) * 4;
    dst[0] = e[0] | ((unsigned)e[1] << 16);
    dst[1] = e[2] | ((unsigned)e[3] << 16);
    dst[2] = e[4] | ((unsigned)e[5] << 16);
    dst[3] = e[6] | ((unsigned)e[7] << 16);
  }
  if (threadIdx.x == 0) {
    float beta = 0.f;
    for (int a = 0; a < 64; ++a) beta += sbk[a] * sbq[a];
    ((float*)ws)[18 * 256] = beta;
  }
}

#define S2L 0.18033688011112042f  /* (1/8) * log2(e) */

// pass1 grid 256: XCD = bid%8 = (b,dc) (R4-validated clean FETCH)
#define DECODE256() \
  int bid = (int)blockIdx.x; \
  int b = bid & 1, dc = (bid >> 1) & 3, h = bid >> 3; \
  const int d0 = dc << 3; \
  const size_t base0 = (size_t)b * 33554432 + h * 32;

// pass2 grid 512
#define DECODE512() \
  int bid = (int)blockIdx.x; \
  int b = bid & 1, dcc = (bid >> 1) & 7, h = bid >> 4; \
  const int d0 = dcc << 2; \
  const size_t base0 = (size_t)b * 33554432 + h * 32;

// full-slice staging in 64 regs; half-issue / half-write granularity
#define STAGE_DEFS(BUF) \
  const int w2 = tid & 15; \
  const int rp0 = tid >> 4; \
  v2f sA[16], sB[16]; \
  auto issueH = [&](int d, int half) { \
    const float* xp = x + base0 + (size_t)d * 1024; \
    _Pragma("unroll") \
    for (int i = 0; i < 8; ++i) { \
      int rp = half * 256 + (i << 5) + rp0; \
      const float* r0 = xp + (size_t)(2 * rp) * NSP + 2 * w2; \
      sA[half * 8 + i] = *(const v2f*)r0; \
      sB[half * 8 + i] = *(const v2f*)(r0 + NSP); \
    } \
  }; \
  auto writeH = [&](int half) { \
    _Pragma("unroll") \
    for (int i = 0; i < 8; ++i) { \
      int rp = half * 256 + (i << 5) + rp0; \
      int t = rp >> 5, c = (rp & 31) << 1; \
      int off = (t << 7) + (((c << 1)) ^ ((t & 7) << 4)); \
      *(unsigned*)(&BUF[(2 * w2) * XSTR + off])     = pk(sA[half * 8 + i].x, sB[half * 8 + i].x); \
      *(unsigned*)(&BUF[(2 * w2 + 1) * XSTR + off]) = pk(sA[half * 8 + i].y, sB[half * 8 + i].y); \
    } \
  };

#define LOADX_DEF(BUF) \
  auto loadX = [&](int loc, v8s fX[2]) { \
    const unsigned char* bp = &BUF[loc * XSTR + (i16 << 7)]; \
    const int sw = (i16 & 7) << 4; \
    _Pragma("unroll") \
    for (int kc = 0; kc < 2; ++kc) { \
      union { v8s v; unsigned long long dd[2]; } u; \
      int o = (kc << 6) + (g << 3); \
      u.dd[0] = *(const unsigned long long*)(bp + (o ^ sw)); \
      u.dd[1] = *(const unsigned long long*)(bp + ((o + 32) ^ sw)); \
      fX[kc] = u.v; \
    } \
  };

// fM (f=0..7) and fUR (f=8,9) fragments read from LDS per use
#define LDF_DEF() \
  auto ldf = [&](int f) -> v8s { \
    union { v8s v; uint4 q; } u; \
    u.q = *(const uint4*)&Wm[(f << 8) + (lane << 2)]; \
    return u.v; \
  };

#define ATTOF_DEF() \
  auto attOf = [&](const v8s fX[2]) -> v4f { \
    v4f accW[4]; \
    _Pragma("unroll") \
    for (int tr = 0; tr < 4; ++tr) { \
      v8s m0 = ldf(2 * tr), m1 = ldf(2 * tr + 1); \
      v4f a = {0.f, 0.f, 0.f, 0.f}; \
      a = __builtin_amdgcn_mfma_f32_16x16x32_bf16(m0, fX[0], a, 0, 0, 0); \
      a = __builtin_amdgcn_mfma_f32_16x16x32_bf16(m1, fX[1], a, 0, 0, 0); \
      accW[tr] = a; \
    } \
    v8s u0 = ldf(8), u1 = ldf(9); \
    v4f au = {0.f, 0.f, 0.f, 0.f}; \
    au = __builtin_amdgcn_mfma_f32_16x16x32_bf16(u0, fX[0], au, 0, 0, 0); \
    au = __builtin_amdgcn_mfma_f32_16x16x32_bf16(u1, fX[1], au, 0, 0, 0); \
    float a1v = au[0] + beta; \
    float a2v = au[1]; \
    float a2s = __shfl(a2v, i16); \
    v4f att; \
    _Pragma("unroll") \
    for (int j = 0; j < 4; ++j) att[j] = __shfl(a1v, 4 * g + j) + a2s; \
    _Pragma("unroll") \
    for (int kc = 0; kc < 2; ++kc) { \
      UF8 w; \
      w.u[0] = pk(accW[2 * kc][0], accW[2 * kc][1]); \
      w.u[1] = pk(accW[2 * kc][2], accW[2 * kc][3]); \
      w.u[2] = pk(accW[2 * kc + 1][0], accW[2 * kc + 1][1]); \
      w.u[3] = pk(accW[2 * kc + 1][2], accW[2 * kc + 1][3]); \
      att = __builtin_amdgcn_mfma_f32_16x16x32_bf16(fX[kc], w.v, att, 0, 0, 0); \
    } \
    return att; \
  };

// feat MFMA for one c-quarter (tn literal!) -> Fb buffer with bank XOR
#define FEATQ(tn, FB) do { \
  _Pragma("unroll") \
  for (int l = 0; l < 4; ++l) { \
    int wq = 4 * wv + l; \
    UF8 fP; fP.u[0] = Pp[l][0]; fP.u[1] = Pp[l][1]; fP.u[2] = 0; fP.u[3] = 0; \
    UF8 fV; fV.u[0] = vp[l][2 * (tn)]; fV.u[1] = vp[l][2 * (tn) + 1]; fV.u[2] = 0; fV.u[3] = 0; \
    v4f ft = {0.f, 0.f, 0.f, 0.f}; \
    ft = __builtin_amdgcn_mfma_f32_16x16x32_bf16(fP.v, fV.v, ft, 0, 0, 0); \
    _Pragma("unroll") \
    for (int j = 0; j < 4; ++j) { \
      int r = (4 * g + j) * 16 + i16; \
      (FB)[r * 33 + (wq ^ g)] = ft[j]; \
    } \
  } \
} while (0)

// ---------------- pass 1: partial Z over an 8-slice d-chunk; deep staging ----------------
__global__ __launch_bounds__(512) void pass1_z(
    const float* __restrict__ x, const unsigned* __restrict__ ws,
    float* __restrict__ zp) {
  __shared__ __align__(16) unsigned char Xbuf[32 * XSTR];   // 65792 B
  __shared__ unsigned Wm[2560];                             // 10240 B  (total 76032)

  const int tid = (int)threadIdx.x;
  const int lane = tid & 63, wv = tid >> 6;
  const int i16 = lane & 15, g = lane >> 4;
  DECODE256();

  for (int o = tid; o < 2560; o += 512) Wm[o] = ws[o];
  const float beta = ((const float*)ws)[4608];

  STAGE_DEFS(Xbuf);
  LOADX_DEF(Xbuf);
  LDF_DEF();
  ATTOF_DEF();

  float Z[4][4] = {};
  issueH(d0, 0); issueH(d0, 1);
  for (int ii = 0; ii < 8; ++ii) {
    const int d = d0 + ii;
    __syncthreads();                 // prev readers done (also covers Wm copy)
    writeH(0); writeH(1);
    __syncthreads();                 // stage complete
    if (ii < 7) issueH(d + 1, 0);    // first half of next slice in flight
    #pragma unroll
    for (int l = 0; l < 2; ++l) {
      v8s fX[2]; loadX(4 * wv + l, fX);
      v4f att = attOf(fX);
      #pragma unroll
      for (int j = 0; j < 4; ++j) Z[l][j] += exp2f(att[j] * S2L);
    }
    if (ii < 7) issueH(d + 1, 1);    // second half in flight
    #pragma unroll
    for (int l = 2; l < 4; ++l) {
      v8s fX[2]; loadX(4 * wv + l, fX);
      v4f att = attOf(fX);
      #pragma unroll
      for (int j = 0; j < 4; ++j) Z[l][j] += exp2f(att[j] * S2L);
    }
  }
  const int locg = b * 1024 + h * 32 + 4 * wv;
  #pragma unroll
  for (int l = 0; l < 4; ++l)
    #pragma unroll
    for (int j = 0; j < 4; ++j)
      zp[(((size_t)dc * 2048 + locg + l) << 8) + (4 * g + j) * 16 + i16] = Z[l][j];
}

// ---------------- pass 2: P, v, feat, out; double-Fb overlay + spread issue ----------------
__global__ __launch_bounds__(512) void pass2_out(
    const float* __restrict__ x, const float* __restrict__ bv,
    const unsigned* __restrict__ ws, const float* __restrict__ zp,
    float* __restrict__ out) {
  __shared__ __align__(16) unsigned char UNI[67584];        // Xbuf(65792) / FbA+FbB(2x33792)
  __shared__ unsigned Wm[2560];                             // 10240 B  (total 77824)

  const int tid = (int)threadIdx.x;
  const int lane = tid & 63, wv = tid >> 6;
  const int i16 = lane & 15, g = lane >> 4;
  DECODE512();

  for (int o = tid; o < 2560; o += 512) Wm[o] = ws[o];
  const float beta = ((const float*)ws)[4608];
  float bvv[4];
  #pragma unroll
  for (int tn = 0; tn < 4; ++tn) bvv[tn] = bv[i16 + 16 * tn];

  // 1/Z from the 4 pass1 chunk partials
  float iZ[4][4];
  #pragma unroll
  for (int l = 0; l < 4; ++l) {
    const int locg = b * 1024 + h * 32 + 4 * wv + l;
    #pragma unroll
    for (int j = 0; j < 4; ++j) {
      float s = 0.f;
      #pragma unroll
      for (int c2 = 0; c2 < 4; ++c2)
        s += zp[(((size_t)c2 * 2048 + locg) << 8) + (4 * g + j) * 16 + i16];
      iZ[l][j] = 1.f / s;
    }
  }

  STAGE_DEFS(UNI);
  LOADX_DEF(UNI);
  LDF_DEF();
  ATTOF_DEF();

  float* FbA = (float*)UNI;
  float* FbB = FbA + 8448;
  const uint4* W4 = (const uint4*)ws;

  auto storeQ = [&](int tn, int d, const float* FB) {
    float* op = out + base0 + (size_t)d * 1024 + (size_t)(16 * tn) * NSP;
    const int w4 = tid & 7, rr = tid >> 3;
    #pragma unroll
    for (int it = 0; it < 4; ++it) {
      int r = (it << 6) + rr;
      const float* fp = &FB[r * 33 + (w4 << 2)];
      float4 val;
      val.x = fp[0 ^ it]; val.y = fp[1 ^ it]; val.z = fp[2 ^ it]; val.w = fp[3 ^ it];
      *(float4*)(op + (size_t)((r >> 4) * 64 + (r & 15)) * NSP + (w4 << 2)) = val;
    }
  };

  issueH(d0, 0); issueH(d0, 1);
  for (int ii = 0; ii < 4; ++ii) {
    const int d = d0 + ii;
    __syncthreads();                 // prev storeQ(3) LDS reads done -> UNI writable
    writeH(0); writeH(1);
    __syncthreads();                 // stage complete

    // ---- P and v for all 4 locs into registers (stage regs dead here) ----
    unsigned Pp[4][2], vp[4][8];
    #pragma unroll
    for (int l = 0; l < 4; ++l) {
      v8s fX[2]; loadX(4 * wv + l, fX);
      v4f att = attOf(fX);
      float p0 = exp2f(att[0] * S2L) * iZ[l][0];
      float p1 = exp2f(att[1] * S2L) * iZ[l][1];
      float p2 = exp2f(att[2] * S2L) * iZ[l][2];
      float p3 = exp2f(att[3] * S2L) * iZ[l][3];
      Pp[l][0] = pk(p0, p1); Pp[l][1] = pk(p2, p3);
      #pragma unroll
      for (int tn = 0; tn < 4; ++tn) {
        UF8 wa, wb;
        wa.q = W4[(10 + 2 * tn) * 64 + lane];
        wb.q = W4[(11 + 2 * tn) * 64 + lane];
        v4f a = {bvv[tn], bvv[tn], bvv[tn], bvv[tn]};
        a = __builtin_amdgcn_mfma_f32_16x16x32_bf16(fX[0], wa.v, a, 0, 0, 0);
        a = __builtin_amdgcn_mfma_f32_16x16x32_bf16(fX[1], wb.v, a, 0, 0, 0);
        vp[l][2 * tn] = pk(a[0], a[1]); vp[l][2 * tn + 1] = pk(a[2], a[3]);
      }
    }
    __syncthreads();                 // all Xbuf reads done -> Fb overlay safe

    FEATQ(0, FbA);
    __syncthreads();
    storeQ(0, d, FbA);
    if (ii < 3) issueH(d + 1, 0);    // next-slice loads fly under FEATQ/store tail
    FEATQ(1, FbB);
    __syncthreads();
    storeQ(1, d, FbB); FEATQ(2, FbA);
    __syncthreads();
    storeQ(2, d, FbA);
    if (ii < 3) issueH(d + 1, 1);
    FEATQ(3, FbB);
    __syncthreads();
    storeQ(3, d, FbB);
  }
}

extern "C" void kernel_launch(void* const* d_in, const int* in_sizes, int n_in,
                              void* d_out, int out_size, void* d_ws, size_t ws_size,
                              hipStream_t stream) {
  const float* x  = (const float*)d_in[0];
  const float* Wk = (const float*)d_in[1];
  const float* bk = (const float*)d_in[2];
  const float* Wq = (const float*)d_in[3];
  const float* bq = (const float*)d_in[4];
  const float* Wv = (const float*)d_in[5];
  const float* bv = (const float*)d_in[6];
  float* out = (float*)d_out;
  unsigned* ws = (unsigned*)d_ws;
  float* zp = (float*)((char*)d_ws + WS_ZP_B);

  prep_kernel<<<1, 512, 0, stream>>>(Wk, bk, Wq, bq, Wv, ws);
  pass1_z<<<256, 512, 0, stream>>>(x, ws, zp);
  pass2_out<<<512, 512, 0, stream>>>(x, bv, ws, zp, out);
}

// Round 12
// 267.654 us; speedup vs baseline: 1.1438x; 1.1393x over previous
//
#include <hip/hip_runtime.h>

typedef short v8s __attribute__((ext_vector_type(8)));
typedef float v4f __attribute__((ext_vector_type(4)));
typedef float v2f __attribute__((ext_vector_type(2)));

#define NSP 32768
#define XSTR 2056            // bytes per w-location in Xbuf (8B aligned, bank-staggered)
#define WS_ZP_B 65536ull     // zp region byte offset in ws

__device__ __forceinline__ unsigned short f2bf(float f) {
  union { float f; unsigned u; } v; v.f = f;
  unsigned r = v.u + 0x7fffu + ((v.u >> 16) & 1u);
  return (unsigned short)(r >> 16);
}
__device__ __forceinline__ unsigned pk(float a, float b) {
  return (unsigned)f2bf(a) | ((unsigned)f2bf(b) << 16);
}

union UF8 { v8s v; unsigned u[4]; uint4 q; };

// k-map convention used CONSISTENTLY for every A and B fragment (errors cancel):
// frag element j of lane (i16 + 16*g) <-> k = 16*(j>>2) + 4*g + (j&3)

__global__ __launch_bounds__(512) void prep_kernel(
    const float* __restrict__ Wk, const float* __restrict__ bk,
    const float* __restrict__ Wq, const float* __restrict__ bq,
    const float* __restrict__ Wv, unsigned* __restrict__ ws) {
  __shared__ float sWk[4096], sWq[4096], sWv[4096], sbk[64], sbq[64];
  for (int i = threadIdx.x; i < 4096; i += 512) { sWk[i] = Wk[i]; sWq[i] = Wq[i]; sWv[i] = Wv[i]; }
  if (threadIdx.x < 64) { sbk[threadIdx.x] = bk[threadIdx.x]; sbq[threadIdx.x] = bq[threadIdx.x]; }
  __syncthreads();
  for (int task = threadIdx.x; task < 18 * 64; task += 512) {
    int f = task >> 6, lane = task & 63;
    int i16 = lane & 15, g = lane >> 4;
    unsigned short e[8];
    #pragma unroll
    for (int j = 0; j < 8; ++j) {
      int k = (((j >> 2) << 4) + 4 * g + (j & 3));
      float acc = 0.f;
      if (f < 8) {
        int row = ((f >> 1) << 4) + i16;
        int cc  = ((f & 1) << 5) + k;
        for (int a = 0; a < 64; ++a) acc += sWk[a * 64 + row] * sWq[a * 64 + cc];
      } else if (f < 10) {
        int c = ((f - 8) << 5) + k;
        if (i16 == 0)      { for (int a = 0; a < 64; ++a) acc += sWk[a * 64 + c] * sbq[a]; }
        else if (i16 == 1) { for (int a = 0; a < 64; ++a) acc += sbk[a] * sWq[a * 64 + c]; }
      } else {
        int c  = (((f - 10) >> 1) << 4) + i16;
        int cp = (((f - 10) & 1) << 5) + k;
        acc = sWv[c * 64 + cp];
      }
      e[j] = f2bf(acc);
    }
    unsigned* dst = ws + (size_t)(f * 64 + lane) * 4;
    dst[0] = e[0] | ((unsigned)e[1] << 16);
    dst[1] = e[2] | ((unsigned)e[3] << 16);
    dst[2] = e[4] | ((unsigned)e[5] << 16);
    dst[3] = e[6] | ((unsigned)e[7] << 16);
  }
  if (threadIdx.x == 0) {
    float beta = 0.f;
    for (int a = 0; a < 64; ++a) beta += sbk[a] * sbq[a];
    ((float*)ws)[18 * 256] = beta;
  }
}

#define S2L 0.18033688011112042f  /* (1/8) * log2(e) */

// pass1 grid 256: XCD = bid%8 = (b,dc)
#define DECODE256() \
  int bid = (int)blockIdx.x; \
  int b = bid & 1, dc = (bid >> 1) & 3, h = bid >> 3; \
  const int d0 = dc << 3; \
  const size_t base0 = (size_t)b * 33554432 + h * 32;

// pass2 grid 512
#define DECODE512() \
  int bid = (int)blockIdx.x; \
  int b = bid & 1, dcc = (bid >> 1) & 7, h = bid >> 4; \
  const int d0 = dcc << 2; \
  const size_t base0 = (size_t)b * 33554432 + h * 32;

// half-slice staging (32 regs peak); EVERY issueH is consumed by the next
// writeH before another issueH runs (R11 bug: two issues clobbered sA/sB)
#define STAGE_DEFS() \
  const int w2 = tid & 15; \
  const int rp0 = tid >> 4; \
  v2f sA[8], sB[8]; \
  auto issueH = [&](int d, int half) { \
    const float* xp = x + base0 + (size_t)d * 1024; \
    _Pragma("unroll") \
    for (int i = 0; i < 8; ++i) { \
      int rp = half * 256 + (i << 5) + rp0; \
      const float* r0 = xp + (size_t)(2 * rp) * NSP + 2 * w2; \
      sA[i] = *(const v2f*)r0; \
      sB[i] = *(const v2f*)(r0 + NSP); \
    } \
  }; \
  auto writeH = [&](unsigned char* BUF, int half) { \
    _Pragma("unroll") \
    for (int i = 0; i < 8; ++i) { \
      int rp = half * 256 + (i << 5) + rp0; \
      int t = rp >> 5, c = (rp & 31) << 1; \
      int off = (t << 7) + (((c << 1)) ^ ((t & 7) << 4)); \
      *(unsigned*)(&BUF[(2 * w2) * XSTR + off])     = pk(sA[i].x, sB[i].x); \
      *(unsigned*)(&BUF[(2 * w2 + 1) * XSTR + off]) = pk(sA[i].y, sB[i].y); \
    } \
  };

#define LOADX_DEF() \
  auto loadX = [&](const unsigned char* BUF, int loc, v8s fX[2]) { \
    const unsigned char* bp = &BUF[loc * XSTR + (i16 << 7)]; \
    const int sw = (i16 & 7) << 4; \
    _Pragma("unroll") \
    for (int kc = 0; kc < 2; ++kc) { \
      union { v8s v; unsigned long long dd[2]; } u; \
      int o = (kc << 6) + (g << 3); \
      u.dd[0] = *(const unsigned long long*)(bp + (o ^ sw)); \
      u.dd[1] = *(const unsigned long long*)(bp + ((o + 32) ^ sw)); \
      fX[kc] = u.v; \
    } \
  };

// weight fragments (fM f=0..7, fUR f=8,9, fWv f=10..17) read from LDS per use
#define LDF_DEF() \
  auto ldf = [&](int f) -> v8s { \
    union { v8s v; uint4 q; } u; \
    u.q = *(const uint4*)&Wm[(f << 8) + (lane << 2)]; \
    return u.v; \
  };

#define ATTOF_DEF() \
  auto attOf = [&](const v8s fX[2]) -> v4f { \
    v4f accW[4]; \
    _Pragma("unroll") \
    for (int tr = 0; tr < 4; ++tr) { \
      v8s m0 = ldf(2 * tr), m1 = ldf(2 * tr + 1); \
      v4f a = {0.f, 0.f, 0.f, 0.f}; \
      a = __builtin_amdgcn_mfma_f32_16x16x32_bf16(m0, fX[0], a, 0, 0, 0); \
      a = __builtin_amdgcn_mfma_f32_16x16x32_bf16(m1, fX[1], a, 0, 0, 0); \
      accW[tr] = a; \
    } \
    v8s u0 = ldf(8), u1 = ldf(9); \
    v4f au = {0.f, 0.f, 0.f, 0.f}; \
    au = __builtin_amdgcn_mfma_f32_16x16x32_bf16(u0, fX[0], au, 0, 0, 0); \
    au = __builtin_amdgcn_mfma_f32_16x16x32_bf16(u1, fX[1], au, 0, 0, 0); \
    float a1v = au[0] + beta; \
    float a2v = au[1]; \
    float a2s = __shfl(a2v, i16); \
    v4f att; \
    _Pragma("unroll") \
    for (int j = 0; j < 4; ++j) att[j] = __shfl(a1v, 4 * g + j) + a2s; \
    _Pragma("unroll") \
    for (int kc = 0; kc < 2; ++kc) { \
      UF8 w; \
      w.u[0] = pk(accW[2 * kc][0], accW[2 * kc][1]); \
      w.u[1] = pk(accW[2 * kc][2], accW[2 * kc][3]); \
      w.u[2] = pk(accW[2 * kc + 1][0], accW[2 * kc + 1][1]); \
      w.u[3] = pk(accW[2 * kc + 1][2], accW[2 * kc + 1][3]); \
      att = __builtin_amdgcn_mfma_f32_16x16x32_bf16(fX[kc], w.v, att, 0, 0, 0); \
    } \
    return att; \
  };

// feat MFMA for one c-quarter (tn literal!) -> Fb buffer with bank XOR
#define FEATQ(tn, FB) do { \
  _Pragma("unroll") \
  for (int l = 0; l < 4; ++l) { \
    int wq = 4 * wv + l; \
    UF8 fP; fP.u[0] = Pp[l][0]; fP.u[1] = Pp[l][1]; fP.u[2] = 0; fP.u[3] = 0; \
    UF8 fV; fV.u[0] = vp[l][2 * (tn)]; fV.u[1] = vp[l][2 * (tn) + 1]; fV.u[2] = 0; fV.u[3] = 0; \
    v4f ft = {0.f, 0.f, 0.f, 0.f}; \
    ft = __builtin_amdgcn_mfma_f32_16x16x32_bf16(fP.v, fV.v, ft, 0, 0, 0); \
    _Pragma("unroll") \
    for (int j = 0; j < 4; ++j) { \
      int r = (4 * g + j) * 16 + i16; \
      (FB)[r * 33 + (wq ^ g)] = ft[j]; \
    } \
  } \
} while (0)

// ---------------- pass 1: partial Z; LDS double-buffer, 1 sync/slice ----------------
__global__ __launch_bounds__(512) void pass1_z(
    const float* __restrict__ x, const unsigned* __restrict__ ws,
    float* __restrict__ zp) {
  __shared__ __align__(16) unsigned char Xd[2][65792];      // 131584 B
  __shared__ unsigned Wm[2560];                             // 10240 B  (total 141824)

  const int tid = (int)threadIdx.x;
  const int lane = tid & 63, wv = tid >> 6;
  const int i16 = lane & 15, g = lane >> 4;
  DECODE256();

  for (int o = tid; o < 2560; o += 512) Wm[o] = ws[o];
  const float beta = ((const float*)ws)[4608];

  STAGE_DEFS();
  LOADX_DEF();
  LDF_DEF();
  ATTOF_DEF();

  float Z[4][4] = {};
  // prologue: stage slice d0 into Xd[0] (each issue consumed immediately)
  issueH(d0, 0); writeH(Xd[0], 0);
  issueH(d0, 1); writeH(Xd[0], 1);
  __syncthreads();
  for (int ii = 0; ii < 8; ++ii) {
    const int d = d0 + ii;
    unsigned char* cur = Xd[ii & 1];
    unsigned char* nxt = Xd[(ii & 1) ^ 1];
    if (ii < 7) issueH(d + 1, 0);          // lands under compute l0,l1
    #pragma unroll
    for (int l = 0; l < 2; ++l) {
      v8s fX[2]; loadX(cur, 4 * wv + l, fX);
      v4f att = attOf(fX);
      #pragma unroll
      for (int j = 0; j < 4; ++j) Z[l][j] += exp2f(att[j] * S2L);
    }
    if (ii < 7) { writeH(nxt, 0); issueH(d + 1, 1); }
    #pragma unroll
    for (int l = 2; l < 4; ++l) {
      v8s fX[2]; loadX(cur, 4 * wv + l, fX);
      v4f att = attOf(fX);
      #pragma unroll
      for (int j = 0; j < 4; ++j) Z[l][j] += exp2f(att[j] * S2L);
    }
    if (ii < 7) writeH(nxt, 1);
    __syncthreads();                       // cur reads done; nxt staged
  }
  const int locg = b * 1024 + h * 32 + 4 * wv;
  #pragma unroll
  for (int l = 0; l < 4; ++l)
    #pragma unroll
    for (int j = 0; j < 4; ++j)
      zp[(((size_t)dc * 2048 + locg + l) << 8) + (4 * g + j) * 16 + i16] = Z[l][j];
}

// ---------------- pass 2: P, v, feat, out; dbuf: stage->B during P/v, Fb on A ----------------
__global__ __launch_bounds__(512) void pass2_out(
    const float* __restrict__ x, const float* __restrict__ bv,
    const unsigned* __restrict__ ws, const float* __restrict__ zp,
    float* __restrict__ out) {
  __shared__ __align__(16) unsigned char Xd[2][67584];      // 135168 B (X-stage or FbA+FbB)
  __shared__ unsigned Wm[4608];                             // 18432 B  (total 153600)

  const int tid = (int)threadIdx.x;
  const int lane = tid & 63, wv = tid >> 6;
  const int i16 = lane & 15, g = lane >> 4;
  DECODE512();

  for (int o = tid; o < 4608; o += 512) Wm[o] = ws[o];
  const float beta = ((const float*)ws)[4608];
  float bvv[4];
  #pragma unroll
  for (int tn = 0; tn < 4; ++tn) bvv[tn] = bv[i16 + 16 * tn];

  // 1/Z from the 4 pass1 chunk partials
  float iZ[4][4];
  #pragma unroll
  for (int l = 0; l < 4; ++l) {
    const int locg = b * 1024 + h * 32 + 4 * wv + l;
    #pragma unroll
    for (int j = 0; j < 4; ++j) {
      float s = 0.f;
      #pragma unroll
      for (int c2 = 0; c2 < 4; ++c2)
        s += zp[(((size_t)c2 * 2048 + locg) << 8) + (4 * g + j) * 16 + i16];
      iZ[l][j] = 1.f / s;
    }
  }

  STAGE_DEFS();
  LOADX_DEF();
  LDF_DEF();
  ATTOF_DEF();

  auto storeQ = [&](int tn, int d, const float* FB) {
    float* op = out + base0 + (size_t)d * 1024 + (size_t)(16 * tn) * NSP;
    const int w4 = tid & 7, rr = tid >> 3;
    #pragma unroll
    for (int it = 0; it < 4; ++it) {
      int r = (it << 6) + rr;
      const float* fp = &FB[r * 33 + (w4 << 2)];
      float4 val;
      val.x = fp[0 ^ it]; val.y = fp[1 ^ it]; val.z = fp[2 ^ it]; val.w = fp[3 ^ it];
      *(float4*)(op + (size_t)((r >> 4) * 64 + (r & 15)) * NSP + (w4 << 2)) = val;
    }
  };

  // prologue: stage slice d0 into Xd[0]
  issueH(d0, 0); writeH(Xd[0], 0);
  issueH(d0, 1); writeH(Xd[0], 1);
  for (int ii = 0; ii < 4; ++ii) {
    const int d = d0 + ii;
    unsigned char* A = Xd[ii & 1];         // current X (read in P/v; Fb after)
    unsigned char* B = Xd[(ii & 1) ^ 1];   // next-slice stage target
    __syncthreads();                       // prologue writes / prev storeQ(3) reads of B done

    // ---- P/v phase: read A; stage d+1 into B interleaved ----
    unsigned Pp[4][2], vp[4][8];
    if (ii < 3) issueH(d + 1, 0);
    #pragma unroll
    for (int l = 0; l < 4; ++l) {
      if (l == 2 && ii < 3) { writeH(B, 0); issueH(d + 1, 1); }
      v8s fX[2]; loadX(A, 4 * wv + l, fX);
      v4f att = attOf(fX);
      float p0 = exp2f(att[0] * S2L) * iZ[l][0];
      float p1 = exp2f(att[1] * S2L) * iZ[l][1];
      float p2 = exp2f(att[2] * S2L) * iZ[l][2];
      float p3 = exp2f(att[3] * S2L) * iZ[l][3];
      Pp[l][0] = pk(p0, p1); Pp[l][1] = pk(p2, p3);
      #pragma unroll
      for (int tn = 0; tn < 4; ++tn) {
        v8s wa = ldf(10 + 2 * tn), wb = ldf(11 + 2 * tn);
        v4f a = {bvv[tn], bvv[tn], bvv[tn], bvv[tn]};
        a = __builtin_amdgcn_mfma_f32_16x16x32_bf16(fX[0], wa, a, 0, 0, 0);
        a = __builtin_amdgcn_mfma_f32_16x16x32_bf16(fX[1], wb, a, 0, 0, 0);
        vp[l][2 * tn] = pk(a[0], a[1]); vp[l][2 * tn + 1] = pk(a[2], a[3]);
      }
    }
    if (ii < 3) writeH(B, 1);
    __syncthreads();                       // A reads done -> Fb overlay on A safe; B staged

    float* FbA = (float*)A;
    float* FbB = FbA + 8448;
    FEATQ(0, FbA);
    __syncthreads();
    storeQ(0, d, FbA); FEATQ(1, FbB);
    __syncthreads();
    storeQ(1, d, FbB); FEATQ(2, FbA);
    __syncthreads();
    storeQ(2, d, FbA); FEATQ(3, FbB);
    __syncthreads();
    storeQ(3, d, FbB);
  }
}

extern "C" void kernel_launch(void* const* d_in, const int* in_sizes, int n_in,
                              void* d_out, int out_size, void* d_ws, size_t ws_size,
                              hipStream_t stream) {
  const float* x  = (const float*)d_in[0];
  const float* Wk = (const float*)d_in[1];
  const float* bk = (const float*)d_in[2];
  const float* bq = (const float*)d_in[4];
  const float* Wq = (const float*)d_in[3];
  const float* Wv = (const float*)d_in[5];
  const float* bv = (const float*)d_in[6];
  float* out = (float*)d_out;
  unsigned* ws = (unsigned*)d_ws;
  float* zp = (float*)((char*)d_ws + WS_ZP_B);

  prep_kernel<<<1, 512, 0, stream>>>(Wk, bk, Wq, bq, Wv, ws);
  pass1_z<<<256, 512, 0, stream>>>(x, ws, zp);
  pass2_out<<<512, 512, 0, stream>>>(x, bv, ws, zp, out);
}